// Round 8
// baseline (280.140 us; speedup 1.0000x reference)
//
#include <hip/hip_runtime.h>
#include <hip/hip_bf16.h>

#define BATCH   32768
#define DM      1024
#define NE      16
#define THRESHF 0.3f
#define MARGIN  0.02f

// ws layout (bytes)
// idx   @ 0          : int32[32768]            = 131072
// ctrl  @ 131072     : u32[2048] (8192 B)
//    [e*16]        counts (one 64B line per expert)
//    [256 + e*16]  cursor (strided)
//    [512..528]    tileBase int[17]
//    [1024..2047]  packT u32[1024] (pm | mm<<16 per dim)
// Qbf   @ 139264     : bf16[16*1024] ternary   = 32768
// perm  @ 172032     : int32[36864]            = 147456 (prefilled 0)
// Xbf   @ 319488     : bf16[32768*1024]        = 67108864
// Wb    @ 67428352   : bf16[16*1024*1024]      = 33554432  (ends ~96.3 MB)
#define CTRL_OFF 131072
#define QBF_OFF  139264
#define PERM_OFF 172032
#define XBF_OFF  319488
#define WB_OFF   67428352ull
#define WS_NEED  (WB_OFF + (size_t)NE * DM * DM * 2)

typedef __attribute__((ext_vector_type(8))) short bf16x8;
typedef __attribute__((ext_vector_type(4))) float f32x4;

#define MFMA16(a, b, c) __builtin_amdgcn_mfma_f32_16x16x32_bf16(a, b, c, 0, 0, 0)

static __device__ __forceinline__ unsigned short f2bf(float f) {
    union { float f; unsigned u; } v; v.f = f;
    unsigned r = (v.u + 0x7FFFu + ((v.u >> 16) & 1u)) >> 16;  // RNE
    return (unsigned short)r;
}
static __device__ __forceinline__ float bf2f(unsigned short h) {
    union { unsigned u; float f; } v; v.u = ((unsigned)h) << 16;
    return v.f;
}

static __device__ __forceinline__ void gload_lds16(const void* g, void* s) {
    __builtin_amdgcn_global_load_lds(
        (const __attribute__((address_space(1))) void*)g,
        (__attribute__((address_space(3))) void*)s, 16, 0, 0);
}

// Zero ctrl, build ternary pack table + bf16 ternary Q, prefill perm with 0.
__global__ void k_init(const float* __restrict__ sig, unsigned* __restrict__ ctrl,
                       int* __restrict__ perm, unsigned short* __restrict__ Qbf) {
    const int t = blockIdx.x * 256 + threadIdx.x;  // 0..16383
    if (t < 544) ctrl[t] = 0;
    if (t < 1024) {
        unsigned pm = 0, mm = 0;
#pragma unroll
        for (int e = 0; e < NE; ++e) {
            float s = sig[e * DM + t];
            pm |= (s > THRESHF ? 1u : 0u) << e;
            mm |= (s < -THRESHF ? 1u : 0u) << e;
        }
        ctrl[1024 + t] = pm | (mm << 16);
    }
    if (t < 9216) ((int4*)perm)[t] = make_int4(0, 0, 0, 0);
    {   // Qbf[e][d], t = e*1024+d
        float s = sig[t];
        Qbf[t] = s > THRESHF ? (unsigned short)0x3F80u
                             : (s < -THRESHF ? (unsigned short)0xBF80u : (unsigned short)0u);
    }
}

// MFMA router: scores = (x_hi @ Q^T) + (x_lo @ Q^T) in bf16 MFMA (f32 acc),
// top-2 margin; exact f64 fallback for close calls; writes Xbf (= x_hi).
__global__ __launch_bounds__(256) void k_router(const float* __restrict__ x,
                                                const unsigned short* __restrict__ Qbf,
                                                unsigned* __restrict__ ctrl,
                                                int* __restrict__ idx,
                                                float* __restrict__ outIdx,
                                                unsigned short* __restrict__ Xbf,
                                                int writeXbf) {
    const int t = threadIdx.x, w = t >> 6, l = t & 63;
    const int lc = l & 15, lr = l >> 4;
    const int wid = blockIdx.x * 4 + w;   // 0..2047
    const int row0 = wid * 16;
    const unsigned* packT = ctrl + 1024;

    const float* ax = x + (size_t)(row0 + lc) * DM + lr * 8;
    const unsigned short* qx = Qbf + (size_t)lc * DM + lr * 8;
    unsigned short* xb = Xbf + (size_t)(row0 + lc) * DM + lr * 8;

    f32x4 acc = (f32x4){0.f, 0.f, 0.f, 0.f};

    for (int kt = 0; kt < 16; ++kt) {
#pragma unroll
        for (int h = 0; h < 2; ++h) {
            const int ko = kt * 64 + h * 32;
            float4 v0 = *(const float4*)(ax + ko);
            float4 v1 = *(const float4*)(ax + ko + 4);
            bf16x8 q = *(const bf16x8*)(qx + ko);

            float f[8] = {v0.x, v0.y, v0.z, v0.w, v1.x, v1.y, v1.z, v1.w};
            bf16x8 ah, al;
#pragma unroll
            for (int j = 0; j < 8; ++j) {
                unsigned short hi = f2bf(f[j]);
                float r = f[j] - bf2f(hi);
                ah[j] = (short)hi;
                al[j] = (short)f2bf(r);
            }
            if (writeXbf) *(bf16x8*)(xb + ko) = ah;
            acc = MFMA16(ah, q, acc);
            acc = MFMA16(al, q, acc);
        }
    }
    // C layout: lane holds scores of expert e=lc for rows lr*4+reg.

    float bv[4]; int bi[4]; float gap[4];
#pragma unroll
    for (int reg = 0; reg < 4; ++reg) {
        float v = acc[reg]; int i = lc; float s = -3.4e38f;
#pragma unroll
        for (int m = 1; m < 16; m <<= 1) {
            float ov = __shfl_xor(v, m, 64);
            int oi = __shfl_xor(i, m, 64);
            float os = __shfl_xor(s, m, 64);
            bool take = (ov > v) || (ov == v && oi < i);
            float loser = take ? v : ov;
            v = take ? ov : v;
            i = take ? oi : i;
            s = fmaxf(fmaxf(s, os), loser);
        }
        bv[reg] = v; bi[reg] = i; gap[reg] = v - s;
    }

    unsigned flagsw = 0;
#pragma unroll
    for (int reg = 0; reg < 4; ++reg)
        flagsw |= (gap[reg] < MARGIN ? 1u : 0u) << reg;

    if (__any(lc == 0 && flagsw != 0)) {   // rare exact path
#pragma unroll
        for (int reg = 0; reg < 4; ++reg) {
            for (int g = 0; g < 4; ++g) {
                const unsigned fw = __shfl(flagsw, g * 16, 64);
                if ((fw >> reg) & 1u) {
                    const int row = row0 + g * 4 + reg;
                    const float* xr = x + (size_t)row * DM;
                    float xv[16]; unsigned mk[16];
#pragma unroll
                    for (int k2 = 0; k2 < 16; ++k2) {
                        xv[k2] = xr[k2 * 64 + l];
                        mk[k2] = packT[k2 * 64 + l];
                    }
                    double best = 0.0; int bbi = 0;
                    for (int e = 0; e < 16; ++e) {
                        double a = 0.0;
#pragma unroll
                        for (int k2 = 0; k2 < 16; ++k2) {
                            const int pb = (int)((mk[k2] >> e) & 1u);
                            const int mb = (int)((mk[k2] >> (16 + e)) & 1u);
                            a += pb ? (double)xv[k2] : (mb ? -(double)xv[k2] : 0.0);
                        }
#pragma unroll
                        for (int m = 1; m < 64; m <<= 1) a += __shfl_xor(a, m, 64);
                        if (e == 0 || a > best) { best = a; bbi = e; }
                    }
                    if (lr == g && lc == 0) bi[reg] = bbi;
                }
            }
        }
    }

    if (lc == 0) {
#pragma unroll
        for (int reg = 0; reg < 4; ++reg) {
            const int row = row0 + lr * 4 + reg;
            idx[row] = bi[reg];
            outIdx[row] = (float)bi[reg];
            atomicAdd(&ctrl[bi[reg] * 16], 1u);
        }
    }
}

// Tile-granular prefix at granularity G: tileBase[e] = #tiles before e.
__global__ void k_scan(unsigned* __restrict__ ctrl, int G) {
    if (threadIdx.x == 0) {
        int* tileBase = (int*)(ctrl + 512);
        int acc = 0;
        for (int e = 0; e < NE; ++e) {
            tileBase[e] = acc;
            acc += (int)((ctrl[e * 16] + (unsigned)(G - 1)) / (unsigned)G);
        }
        tileBase[NE] = acc;
    }
}

// Perm build: block-aggregated ranks (LDS hist -> 16 global atomics/block).
__global__ __launch_bounds__(256) void k_perm(const int* __restrict__ idx,
                                              unsigned* __restrict__ ctrl,
                                              int* __restrict__ perm, int G) {
    __shared__ unsigned hcnt[16];
    __shared__ unsigned hbase[16];
    const int t = threadIdx.x;
    const int row = blockIdx.x * 256 + t;
    const int* tileBase = (const int*)(ctrl + 512);
    if (t < 16) hcnt[t] = 0;
    __syncthreads();
    const int e = idx[row];
    const unsigned lrank = atomicAdd(&hcnt[e], 1u);
    __syncthreads();
    if (t < 16) hbase[t] = atomicAdd(&ctrl[256 + t * 16], hcnt[t]);
    __syncthreads();
    perm[tileBase[e] * G + hbase[e] + lrank] = row;
}

// W f32 -> bf16 (16M elems, 8 per thread).
__global__ __launch_bounds__(256) void k_convw(const float* __restrict__ W,
                                               unsigned short* __restrict__ Wb) {
    const size_t g = ((size_t)blockIdx.x * 256 + threadIdx.x) * 8;
    float4 a = *(const float4*)&W[g];
    float4 b = *(const float4*)&W[g + 4];
    *(ushort4*)&Wb[g]     = make_ushort4(f2bf(a.x), f2bf(a.y), f2bf(a.z), f2bf(a.w));
    *(ushort4*)&Wb[g + 4] = make_ushort4(f2bf(b.x), f2bf(b.y), f2bf(b.z), f2bf(b.w));
}

// ---------------- 256x256 8-phase grouped GEMM (m201-style) ----------------
// BM=BN=256, BK=64, 8 waves (2M x 4N), per-wave out 128x64, LDS 128KB dbuf.
// Swizzle: row r, 16B-slot s holds data-chunk d=(s-(r&7))&7 (both-sides).
// Stage: thread c sources chunk d=((l&7)-(l>>3))&7, LDS dest lane-linear.
// Per K-tile: 4 phases {A-frag ds_reads | 2 gload_lds | barrier | 16 MFMA}.
// vmcnt(2) once per K-tile (counted, never 0 in main loop except last).
// B chunks staged p0/p1 (consumed p0 of t+1), A chunks p2/p3 (chunk q -> phase q).
#define LDA(Ab, mf, ks) \
    (*(const bf16x8*)&(Ab)[(((wr * 128 + (mf) * 16 + lc) * 8 + \
                             (((ks) * 4 + lr + (lc & 7)) & 7)) * 8)])
#define LDB(Bb, nf, ks) \
    (*(const bf16x8*)&(Bb)[(((wc * 64 + (nf) * 16 + lc) * 8 + \
                             (((ks) * 4 + lr + (lc & 7)) & 7)) * 8)])

__global__ __launch_bounds__(512, 2) void k_gemm256(
        const unsigned short* __restrict__ Xbf,
        const unsigned short* __restrict__ Wb,
        const float* __restrict__ bias,
        const int* __restrict__ perm,
        const unsigned* __restrict__ ctrl,
        float* __restrict__ out) {
    __shared__ unsigned short Al[2][16384];
    __shared__ unsigned short Bl[2][16384];

    const int* tileBase = (const int*)(ctrl + 512);
    // 576 blocks: xcd = flat&7; per-XCD: 18 bx x 4 ny (ny-siblings share XCD L2)
    int bx, ny;
    {
        const int flat = blockIdx.x;
        const int xcd = flat & 7, s2 = flat >> 3;
        bx = xcd * 18 + (s2 >> 2);
        ny = s2 & 3;
    }
    const int total = tileBase[NE];
    if (bx >= total) return;
    int e = 0;
    while (e < NE - 1 && tileBase[e + 1] <= bx) ++e;
    const int valid = (int)ctrl[e * 16] - (bx - tileBase[e]) * 256;  // 1..256
    const int n0 = ny * 256;

    const int t = threadIdx.x, w = t >> 6, l = t & 63;
    const int lc = l & 15, lr = l >> 4;
    const int wr = w >> 2, wc = w & 3;
    const int j = (w << 3) + (l >> 3);          // global 16B-chunk row index
    const int d = ((l & 7) - (l >> 3)) & 7;     // source data-chunk (inv swizzle)
    const size_t prB = (size_t)bx * 256;

    // Stage sources + LDS bases.
    const unsigned short* asrc[4];
    const unsigned short* bsrc[4];
    int aB[4], bB[4];
#pragma unroll
    for (int q = 0; q < 4; ++q) {
        const int ra = q * 32 + (j & 31) + (j >> 5) * 128;       // A chunk rows
        asrc[q] = Xbf + (size_t)perm[prB + ra] * DM + d * 8;
        const int rb = (j >> 4) * 64 + q * 16 + (j & 15);        // B chunk rows
        bsrc[q] = Wb + ((size_t)e * DM + n0 + rb) * DM + d * 8;
        aB[q] = (q * 256 + (w >> 2) * 1024 + (w & 3) * 64) * 8;  // ushort idx
        bB[q] = ((w >> 1) * 512 + q * 128 + (w & 1) * 64) * 8;
    }

    f32x4 acc[8][4];
#pragma unroll
    for (int m = 0; m < 8; ++m)
#pragma unroll
        for (int n = 0; n < 4; ++n) acc[m][n] = (f32x4){0.f, 0.f, 0.f, 0.f};

    // Prologue: stage K-tile 0 into buf 0 (8 loads).
#pragma unroll
    for (int q = 0; q < 4; ++q) gload_lds16(bsrc[q], &Bl[0][bB[q]]);
#pragma unroll
    for (int q = 0; q < 4; ++q) gload_lds16(asrc[q], &Al[0][aB[q]]);

    const int NT = DM / 64;  // 16
    for (int kt = 0; kt < NT; ++kt) {
        const int buf = kt & 1;
        const unsigned short* Ab = Al[buf];
        const unsigned short* Bb = Bl[buf];
        unsigned short* An = Al[buf ^ 1];
        unsigned short* Bn = Bl[buf ^ 1];
        const int ko = (kt + 1) * 64;
        const bool more = (kt + 1 < NT);

        // ---- phase 0: stage B0,B1(t+1); vmcnt; barrier; read B + A(0,1); MFMA
        if (more) {
            gload_lds16(bsrc[0] + ko, Bn + bB[0]);
            gload_lds16(bsrc[1] + ko, Bn + bB[1]);
            asm volatile("s_waitcnt vmcnt(2)" ::: "memory");
        } else {
            asm volatile("s_waitcnt vmcnt(0)" ::: "memory");
        }
        __builtin_amdgcn_sched_barrier(0);
        __builtin_amdgcn_s_barrier();
        __builtin_amdgcn_sched_barrier(0);

        bf16x8 bfr[4][2];
#pragma unroll
        for (int nf = 0; nf < 4; ++nf) {
            bfr[nf][0] = LDB(Bb, nf, 0);
            bfr[nf][1] = LDB(Bb, nf, 1);
        }
        {
            bf16x8 a00 = LDA(Ab, 0, 0), a01 = LDA(Ab, 0, 1);
            bf16x8 a10 = LDA(Ab, 1, 0), a11 = LDA(Ab, 1, 1);
            __builtin_amdgcn_s_setprio(1);
#pragma unroll
            for (int nf = 0; nf < 4; ++nf) {
                acc[0][nf] = MFMA16(a00, bfr[nf][0], acc[0][nf]);
                acc[0][nf] = MFMA16(a01, bfr[nf][1], acc[0][nf]);
                acc[1][nf] = MFMA16(a10, bfr[nf][0], acc[1][nf]);
                acc[1][nf] = MFMA16(a11, bfr[nf][1], acc[1][nf]);
            }
            __builtin_amdgcn_s_setprio(0);
        }
        __builtin_amdgcn_s_barrier();

        // ---- phase 1: read A(2,3); stage B2,B3; barrier; MFMA
        {
            bf16x8 a00 = LDA(Ab, 2, 0), a01 = LDA(Ab, 2, 1);
            bf16x8 a10 = LDA(Ab, 3, 0), a11 = LDA(Ab, 3, 1);
            if (more) {
                gload_lds16(bsrc[2] + ko, Bn + bB[2]);
                gload_lds16(bsrc[3] + ko, Bn + bB[3]);
            }
            __builtin_amdgcn_s_barrier();
            __builtin_amdgcn_sched_barrier(0);
            __builtin_amdgcn_s_setprio(1);
#pragma unroll
            for (int nf = 0; nf < 4; ++nf) {
                acc[2][nf] = MFMA16(a00, bfr[nf][0], acc[2][nf]);
                acc[2][nf] = MFMA16(a01, bfr[nf][1], acc[2][nf]);
                acc[3][nf] = MFMA16(a10, bfr[nf][0], acc[3][nf]);
                acc[3][nf] = MFMA16(a11, bfr[nf][1], acc[3][nf]);
            }
            __builtin_amdgcn_s_setprio(0);
        }
        __builtin_amdgcn_s_barrier();

        // ---- phase 2: read A(4,5); stage A0,A1; barrier; MFMA
        {
            bf16x8 a00 = LDA(Ab, 4, 0), a01 = LDA(Ab, 4, 1);
            bf16x8 a10 = LDA(Ab, 5, 0), a11 = LDA(Ab, 5, 1);
            if (more) {
                gload_lds16(asrc[0] + ko, An + aB[0]);
                gload_lds16(asrc[1] + ko, An + aB[1]);
            }
            __builtin_amdgcn_s_barrier();
            __builtin_amdgcn_sched_barrier(0);
            __builtin_amdgcn_s_setprio(1);
#pragma unroll
            for (int nf = 0; nf < 4; ++nf) {
                acc[4][nf] = MFMA16(a00, bfr[nf][0], acc[4][nf]);
                acc[4][nf] = MFMA16(a01, bfr[nf][1], acc[4][nf]);
                acc[5][nf] = MFMA16(a10, bfr[nf][0], acc[5][nf]);
                acc[5][nf] = MFMA16(a11, bfr[nf][1], acc[5][nf]);
            }
            __builtin_amdgcn_s_setprio(0);
        }
        __builtin_amdgcn_s_barrier();

        // ---- phase 3: read A(6,7); stage A2,A3; barrier; MFMA
        {
            bf16x8 a00 = LDA(Ab, 6, 0), a01 = LDA(Ab, 6, 1);
            bf16x8 a10 = LDA(Ab, 7, 0), a11 = LDA(Ab, 7, 1);
            if (more) {
                gload_lds16(asrc[2] + ko, An + aB[2]);
                gload_lds16(asrc[3] + ko, An + aB[3]);
            }
            __builtin_amdgcn_s_barrier();
            __builtin_amdgcn_sched_barrier(0);
            __builtin_amdgcn_s_setprio(1);
#pragma unroll
            for (int nf = 0; nf < 4; ++nf) {
                acc[6][nf] = MFMA16(a00, bfr[nf][0], acc[6][nf]);
                acc[6][nf] = MFMA16(a01, bfr[nf][1], acc[6][nf]);
                acc[7][nf] = MFMA16(a10, bfr[nf][0], acc[7][nf]);
                acc[7][nf] = MFMA16(a11, bfr[nf][1], acc[7][nf]);
            }
            __builtin_amdgcn_s_setprio(0);
        }
        __builtin_amdgcn_s_barrier();
    }

    // Epilogue: +bias, ReLU, +bf16 residual, scatter rows via perm.
    float bvv[4];
#pragma unroll
    for (int nf = 0; nf < 4; ++nf)
        bvv[nf] = bias[e * DM + n0 + wc * 64 + nf * 16 + lc];

#pragma unroll
    for (int mf = 0; mf < 8; ++mf) {
#pragma unroll
        for (int reg = 0; reg < 4; ++reg) {
            const int rit = wr * 128 + mf * 16 + lr * 4 + reg;
            if (rit < valid) {
                const int orow = perm[prB + rit];
                float* op = out + (size_t)orow * DM;
                const unsigned short* xr = Xbf + (size_t)orow * DM;
#pragma unroll
                for (int nf = 0; nf < 4; ++nf) {
                    const int col = n0 + wc * 64 + nf * 16 + lc;
                    float v = acc[mf][nf][reg] + bvv[nf];
                    v = v > 0.f ? v : 0.f;
                    op[col] = v + bf2f(xr[col]);
                }
            }
        }
    }
}

// Fallback (small ws): 128x128 2-phase reg-staged f32->bf16 (G=128).
__global__ __launch_bounds__(256) void k_gemm_small(
        const float* __restrict__ x, const float* __restrict__ W,
        const float* __restrict__ bias, const int* __restrict__ perm,
        const unsigned* __restrict__ ctrl, float* __restrict__ out) {
    __shared__ unsigned short A_lds[128 * 32];
    __shared__ unsigned short B_lds[128 * 32];
    const int* tileBase = (const int*)(ctrl + 512);
    int bx, ny;
    {
        const int flat = blockIdx.x;
        const int xcd = flat & 7, s2 = flat >> 3;
        bx = xcd * 34 + (s2 >> 3);
        ny = s2 & 7;
    }
    const int total = tileBase[NE];
    if (bx >= total) return;
    int e = 0;
    while (e < NE - 1 && tileBase[e + 1] <= bx) ++e;
    const int valid = (int)ctrl[e * 16] - (bx - tileBase[e]) * 128;
    const int n0 = ny * 128;
    const int t = threadIdx.x, w = t >> 6, l = t & 63;
    const int wr = w >> 1, wc = w & 1;
    const int lc = l & 15, lr = l >> 4;
    const int hsw = ((t & 3) - ((t >> 3) & 3)) & 3;
    const int ssw = (lr + (lc >> 1)) & 3;

    f32x4 acc[4][4];
#pragma unroll
    for (int m = 0; m < 4; ++m)
#pragma unroll
        for (int n = 0; n < 4; ++n) acc[m][n] = (f32x4){0.f, 0.f, 0.f, 0.f};
    const size_t aRowBase = (size_t)bx * 128;

    for (int kt = 0; kt < DM / 32; ++kt) {
        __syncthreads();
#pragma unroll
        for (int rd = 0; rd < 2; ++rd) {
            const int c = rd * 256 + t;
            const int r = c >> 2;
            const float* wp = W + ((size_t)e * DM + n0 + r) * DM + kt * 32 + hsw * 8;
            float4 q0 = *(const float4*)wp;
            float4 q1 = *(const float4*)(wp + 4);
            *(ushort4*)&B_lds[c * 8]     = make_ushort4(f2bf(q0.x), f2bf(q0.y), f2bf(q0.z), f2bf(q0.w));
            *(ushort4*)&B_lds[c * 8 + 4] = make_ushort4(f2bf(q1.x), f2bf(q1.y), f2bf(q1.z), f2bf(q1.w));
            ushort4 p0 = make_ushort4(0, 0, 0, 0), p1 = p0;
            if (r < valid) {
                const int orow = perm[aRowBase + r];
                const float* xp = x + (size_t)orow * DM + kt * 32 + hsw * 8;
                float4 u0 = *(const float4*)xp;
                float4 u1 = *(const float4*)(xp + 4);
                p0 = make_ushort4(f2bf(u0.x), f2bf(u0.y), f2bf(u0.z), f2bf(u0.w));
                p1 = make_ushort4(f2bf(u1.x), f2bf(u1.y), f2bf(u1.z), f2bf(u1.w));
            }
            *(ushort4*)&A_lds[c * 8]     = p0;
            *(ushort4*)&A_lds[c * 8 + 4] = p1;
        }
        __syncthreads();
        bf16x8 af[4], bf[4];
#pragma unroll
        for (int m = 0; m < 4; ++m)
            af[m] = *(const bf16x8*)&A_lds[(wr * 64 + m * 16 + lc) * 32 + ssw * 8];
#pragma unroll
        for (int n = 0; n < 4; ++n)
            bf[n] = *(const bf16x8*)&B_lds[(wc * 64 + n * 16 + lc) * 32 + ssw * 8];
#pragma unroll
        for (int m = 0; m < 4; ++m)
#pragma unroll
            for (int n = 0; n < 4; ++n)
                acc[m][n] = MFMA16(af[m], bf[n], acc[m][n]);
    }

    float bvv[4];
#pragma unroll
    for (int n = 0; n < 4; ++n) bvv[n] = bias[e * DM + n0 + wc * 64 + n * 16 + lc];
#pragma unroll
    for (int m = 0; m < 4; ++m)
#pragma unroll
        for (int reg = 0; reg < 4; ++reg) {
            const int rit = wr * 64 + m * 16 + lr * 4 + reg;
            if (rit < valid) {
                const int orow = perm[aRowBase + rit];
                const float* xr = x + (size_t)orow * DM;
                float* op = out + (size_t)orow * DM;
#pragma unroll
                for (int n = 0; n < 4; ++n) {
                    const int col = n0 + wc * 64 + n * 16 + lc;
                    float v = acc[m][n][reg] + bvv[n];
                    v = v > 0.f ? v : 0.f;
                    op[col] = v + xr[col];
                }
            }
        }
}

extern "C" void kernel_launch(void* const* d_in, const int* in_sizes, int n_in,
                              void* d_out, int out_size, void* d_ws, size_t ws_size,
                              hipStream_t stream) {
    const float* x    = (const float*)d_in[0];
    const float* sig  = (const float*)d_in[1];
    const float* W    = (const float*)d_in[2];
    const float* bias = (const float*)d_in[3];
    float* out = (float*)d_out;
    float* outIdx = out + (size_t)BATCH * DM;

    char* ws = (char*)d_ws;
    int* idx = (int*)ws;
    unsigned* ctrl = (unsigned*)(ws + CTRL_OFF);
    unsigned short* Qbf = (unsigned short*)(ws + QBF_OFF);
    int* perm = (int*)(ws + PERM_OFF);
    unsigned short* Xbf = (unsigned short*)(ws + XBF_OFF);
    unsigned short* Wb = (unsigned short*)(ws + WB_OFF);

    const bool full = ws_size >= WS_NEED;
    const int G = full ? 256 : 128;

    k_init<<<64, 256, 0, stream>>>(sig, ctrl, perm, Qbf);
    k_router<<<512, 256, 0, stream>>>(x, Qbf, ctrl, idx, outIdx, Xbf, full ? 1 : 0);
    k_scan<<<1, 64, 0, stream>>>(ctrl, G);
    k_perm<<<128, 256, 0, stream>>>(idx, ctrl, perm, G);
    if (full) {
        k_convw<<<8192, 256, 0, stream>>>(W, Wb);
        k_gemm256<<<576, 512, 0, stream>>>(Xbf, Wb, bias, perm, ctrl, out);
    } else {
        k_gemm_small<<<2176, 256, 0, stream>>>(x, W, bias, perm, ctrl, out);
    }
}

// Round 9
// 255.269 us; speedup vs baseline: 1.0974x; 1.0974x over previous
//
#include <hip/hip_runtime.h>
#include <hip/hip_bf16.h>

#define BATCH   32768
#define DM      1024
#define NE      16
#define THRESHF 0.3f
#define MARGIN  0.02f

// ws layout (bytes)
// idx   @ 0          : int32[32768]            = 131072
// ctrl  @ 131072     : u32[2048] (8192 B)
//    [e*16]        counts (one 64B line per expert)
//    [256 + e*16]  cursor (strided)
//    [1024..2047]  packT u32[1024] (pm | mm<<16 per dim)
// Qbf   @ 139264     : bf16[16*1024] ternary   = 32768
// perm  @ 172032     : int32[36864]            = 147456 (prefilled 0)
// Xbf   @ 319488     : bf16[32768*1024]        = 67108864
// Wb    @ 67428352   : bf16[16*1024*1024]      = 33554432  (ends ~96.3 MB)
#define CTRL_OFF 131072
#define QBF_OFF  139264
#define PERM_OFF 172032
#define XBF_OFF  319488
#define WB_OFF   67428352ull
#define WS_NEED  (WB_OFF + (size_t)NE * DM * DM * 2)

typedef __attribute__((ext_vector_type(8))) short bf16x8;
typedef __attribute__((ext_vector_type(4))) float f32x4;

#define MFMA16(a, b, c) __builtin_amdgcn_mfma_f32_16x16x32_bf16(a, b, c, 0, 0, 0)

static __device__ __forceinline__ unsigned short f2bf(float f) {
    union { float f; unsigned u; } v; v.f = f;
    unsigned r = (v.u + 0x7FFFu + ((v.u >> 16) & 1u)) >> 16;  // RNE
    return (unsigned short)r;
}
static __device__ __forceinline__ float bf2f(unsigned short h) {
    union { unsigned u; float f; } v; v.u = ((unsigned)h) << 16;
    return v.f;
}

static __device__ __forceinline__ void gload_lds16(const void* g, void* s) {
    __builtin_amdgcn_global_load_lds(
        (const __attribute__((address_space(1))) void*)g,
        (__attribute__((address_space(3))) void*)s, 16, 0, 0);
}

// Local tile-base from final counts (replaces k_scan dispatch): 16 adds.
static __device__ __forceinline__ int tile_base(const unsigned* ctrl, int* tb) {
    int acc = 0;
#pragma unroll
    for (int e = 0; e < NE; ++e) {
        tb[e] = acc;
        acc += (int)((ctrl[e * 16] + 127u) >> 7);
    }
    tb[NE] = acc;
    return acc;
}

// Zero ctrl, build ternary pack table + bf16 ternary Q, prefill perm with 0.
__global__ void k_init(const float* __restrict__ sig, unsigned* __restrict__ ctrl,
                       int* __restrict__ perm, unsigned short* __restrict__ Qbf) {
    const int t = blockIdx.x * 256 + threadIdx.x;  // 0..16383
    if (t < 544) ctrl[t] = 0;
    if (t < 1024) {
        unsigned pm = 0, mm = 0;
#pragma unroll
        for (int e = 0; e < NE; ++e) {
            float s = sig[e * DM + t];
            pm |= (s > THRESHF ? 1u : 0u) << e;
            mm |= (s < -THRESHF ? 1u : 0u) << e;
        }
        ctrl[1024 + t] = pm | (mm << 16);
    }
    if (t < 9216) ((int4*)perm)[t] = make_int4(0, 0, 0, 0);
    {   // Qbf[e][d], t = e*1024+d
        float s = sig[t];
        Qbf[t] = s > THRESHF ? (unsigned short)0x3F80u
                             : (s < -THRESHF ? (unsigned short)0xBF80u : (unsigned short)0u);
    }
}

// MFMA router: scores = (x_hi @ Q^T) + (x_lo @ Q^T) in bf16 MFMA (f32 acc),
// top-2 margin; exact f64 fallback for close calls; writes Xbf (= x_hi).
__global__ __launch_bounds__(256) void k_router(const float* __restrict__ x,
                                                const unsigned short* __restrict__ Qbf,
                                                unsigned* __restrict__ ctrl,
                                                int* __restrict__ idx,
                                                float* __restrict__ outIdx,
                                                unsigned short* __restrict__ Xbf,
                                                int writeXbf) {
    const int t = threadIdx.x, w = t >> 6, l = t & 63;
    const int lc = l & 15, lr = l >> 4;
    const int wid = blockIdx.x * 4 + w;   // 0..2047
    const int row0 = wid * 16;
    const unsigned* packT = ctrl + 1024;

    const float* ax = x + (size_t)(row0 + lc) * DM + lr * 8;
    const unsigned short* qx = Qbf + (size_t)lc * DM + lr * 8;
    unsigned short* xb = Xbf + (size_t)(row0 + lc) * DM + lr * 8;

    f32x4 acc = (f32x4){0.f, 0.f, 0.f, 0.f};

    for (int kt = 0; kt < 16; ++kt) {
#pragma unroll
        for (int h = 0; h < 2; ++h) {
            const int ko = kt * 64 + h * 32;
            float4 v0 = *(const float4*)(ax + ko);
            float4 v1 = *(const float4*)(ax + ko + 4);
            bf16x8 q = *(const bf16x8*)(qx + ko);

            float f[8] = {v0.x, v0.y, v0.z, v0.w, v1.x, v1.y, v1.z, v1.w};
            bf16x8 ah, al;
#pragma unroll
            for (int j = 0; j < 8; ++j) {
                unsigned short hi = f2bf(f[j]);
                float r = f[j] - bf2f(hi);
                ah[j] = (short)hi;
                al[j] = (short)f2bf(r);
            }
            if (writeXbf) *(bf16x8*)(xb + ko) = ah;
            acc = MFMA16(ah, q, acc);
            acc = MFMA16(al, q, acc);
        }
    }
    // C layout: lane holds scores of expert e=lc for rows lr*4+reg.

    float bv[4]; int bi[4]; float gap[4];
#pragma unroll
    for (int reg = 0; reg < 4; ++reg) {
        float v = acc[reg]; int i = lc; float s = -3.4e38f;
#pragma unroll
        for (int m = 1; m < 16; m <<= 1) {
            float ov = __shfl_xor(v, m, 64);
            int oi = __shfl_xor(i, m, 64);
            float os = __shfl_xor(s, m, 64);
            bool take = (ov > v) || (ov == v && oi < i);
            float loser = take ? v : ov;
            v = take ? ov : v;
            i = take ? oi : i;
            s = fmaxf(fmaxf(s, os), loser);
        }
        bv[reg] = v; bi[reg] = i; gap[reg] = v - s;
    }

    unsigned flagsw = 0;
#pragma unroll
    for (int reg = 0; reg < 4; ++reg)
        flagsw |= (gap[reg] < MARGIN ? 1u : 0u) << reg;

    if (__any(lc == 0 && flagsw != 0)) {   // rare exact path
#pragma unroll
        for (int reg = 0; reg < 4; ++reg) {
            for (int g = 0; g < 4; ++g) {
                const unsigned fw = __shfl(flagsw, g * 16, 64);
                if ((fw >> reg) & 1u) {
                    const int row = row0 + g * 4 + reg;
                    const float* xr = x + (size_t)row * DM;
                    float xv[16]; unsigned mk[16];
#pragma unroll
                    for (int k2 = 0; k2 < 16; ++k2) {
                        xv[k2] = xr[k2 * 64 + l];
                        mk[k2] = packT[k2 * 64 + l];
                    }
                    double best = 0.0; int bbi = 0;
                    for (int e = 0; e < 16; ++e) {
                        double a = 0.0;
#pragma unroll
                        for (int k2 = 0; k2 < 16; ++k2) {
                            const int pb = (int)((mk[k2] >> e) & 1u);
                            const int mb = (int)((mk[k2] >> (16 + e)) & 1u);
                            a += pb ? (double)xv[k2] : (mb ? -(double)xv[k2] : 0.0);
                        }
#pragma unroll
                        for (int m = 1; m < 64; m <<= 1) a += __shfl_xor(a, m, 64);
                        if (e == 0 || a > best) { best = a; bbi = e; }
                    }
                    if (lr == g && lc == 0) bi[reg] = bbi;
                }
            }
        }
    }

    if (lc == 0) {
#pragma unroll
        for (int reg = 0; reg < 4; ++reg) {
            const int row = row0 + lr * 4 + reg;
            idx[row] = bi[reg];
            outIdx[row] = (float)bi[reg];
            atomicAdd(&ctrl[bi[reg] * 16], 1u);
        }
    }
}

// Fused: blocks 0..127 build perm (block-aggregated ranks, local tileBase);
// blocks 128.. convert W f32->bf16 (8 elems/thread).
__global__ __launch_bounds__(256) void k_permconv(const int* __restrict__ idx,
                                                  unsigned* __restrict__ ctrl,
                                                  int* __restrict__ perm,
                                                  const float* __restrict__ W,
                                                  unsigned short* __restrict__ Wb) {
    if (blockIdx.x >= 128) {
        const size_t g = ((size_t)(blockIdx.x - 128) * 256 + threadIdx.x) * 8;
        float4 a = *(const float4*)&W[g];
        float4 b = *(const float4*)&W[g + 4];
        *(ushort4*)&Wb[g]     = make_ushort4(f2bf(a.x), f2bf(a.y), f2bf(a.z), f2bf(a.w));
        *(ushort4*)&Wb[g + 4] = make_ushort4(f2bf(b.x), f2bf(b.y), f2bf(b.z), f2bf(b.w));
        return;
    }
    __shared__ unsigned hcnt[16];
    __shared__ unsigned hbase[16];
    const int t = threadIdx.x;
    const int row = blockIdx.x * 256 + t;
    int tb[NE + 1];
    tile_base(ctrl, tb);
    if (t < 16) hcnt[t] = 0;
    __syncthreads();
    const int e = idx[row];
    const unsigned lrank = atomicAdd(&hcnt[e], 1u);
    __syncthreads();
    if (t < 16) hbase[t] = atomicAdd(&ctrl[256 + t * 16], hcnt[t]);
    __syncthreads();
    perm[tb[e] * 128 + hbase[e] + lrank] = row;
}

// Grouped bf16 GEMM: 128x128 tile, BK=32, 4 waves (2x2), 16x16x32 MFMA.
// LDS chunk-swizzle (both-sides, rule #21) — conflict-free (verified R6: 0).
// Asymmetric pipeline (R9): A triple-buffered (depth-2: gathered Xbf rows may
// miss to HBM ~900cy), B double-buffered (depth-1: Wb is L2-shared). 40 KB LDS
// -> 4 blocks/CU (TLP; R8 lesson: blocks/CU beat schedule depth here).
// Per iter t: s_waitcnt vmcnt(2) [leaves A(t+1) in flight; B(t),A(t) landed],
// s_barrier, issue B(t+1)->Bbuf^1 then A(t+2)->Abuf[(t+2)%3], ds_read+MFMA.
// Race audit: stage(t+1/t+2) overwrites buffers whose iter-(t-1) readers all
// completed their lgkm-dependent MFMAs before reaching the iter-t barrier.
__global__ __launch_bounds__(256, 4) void k_gemm(
        const unsigned short* __restrict__ Xbf,
        const unsigned short* __restrict__ Wb,
        const float* __restrict__ bias,
        const int* __restrict__ perm,
        const unsigned* __restrict__ ctrl,
        float* __restrict__ out) {
    __shared__ unsigned short A_lds[3][128 * 32];
    __shared__ unsigned short B_lds[2][128 * 32];

    int tb[NE + 1];
    const int total = tile_base(ctrl, tb);

    // flat = 0..2175: xcd = flat&7; all 8 ny-siblings of one bx share an XCD.
    int bx, ny;
    {
        const int flat = blockIdx.x;
        const int xcd = flat & 7, s2 = flat >> 3;
        bx = xcd * 34 + (s2 >> 3);
        ny = s2 & 7;
    }
    if (bx >= total) return;
    int e = 0;
    while (e < NE - 1 && tb[e + 1] <= bx) ++e;
    const int valid = (int)ctrl[e * 16] - (bx - tb[e]) * 128;  // 1..128
    const int n0 = ny * 128;

    const int t = threadIdx.x, w = t >> 6, l = t & 63;
    const int wr = w >> 1, wc = w & 1;
    const int lc = l & 15, lr = l >> 4;
    const int hsw = ((t & 3) - ((t >> 3) & 3)) & 3;     // staged data-chunk
    const int ssw = (lr + (lc >> 1)) & 3;               // read slot-chunk

    f32x4 acc[4][4];
#pragma unroll
    for (int m = 0; m < 4; ++m)
#pragma unroll
        for (int n = 0; n < 4; ++n) acc[m][n] = (f32x4){0.f, 0.f, 0.f, 0.f};

    const size_t aRowBase = (size_t)bx * 128;
    const unsigned short* Bg = Wb + ((size_t)e * DM + n0) * DM;

    // Per-lane gathered A sources (perm prefilled 0 for pad slots).
    const int r0 = t >> 2;
    const int prow0 = perm[aRowBase + r0];
    const int prow1 = perm[aRowBase + 64 + r0];
    const unsigned short* a0 = Xbf + (size_t)prow0 * DM + hsw * 8;
    const unsigned short* a1 = Xbf + (size_t)prow1 * DM + hsw * 8;
    const unsigned short* b0 = Bg + (size_t)(t >> 2) * DM + hsw * 8;
    const unsigned short* b1 = Bg + (size_t)(64 + (t >> 2)) * DM + hsw * 8;

    auto STAGE_A = [&](int kt, int buf) {   // 2 VMEM instr/thread
        const int ko = kt * 32;
        gload_lds16(a0 + ko, &A_lds[buf][(size_t)(w * 64) * 8]);
        gload_lds16(a1 + ko, &A_lds[buf][(size_t)(256 + w * 64) * 8]);
    };
    auto STAGE_B = [&](int kt, int buf) {   // 2 VMEM instr/thread
        const int ko = kt * 32;
        gload_lds16(b0 + ko, &B_lds[buf][(size_t)(w * 64) * 8]);
        gload_lds16(b1 + ko, &B_lds[buf][(size_t)(256 + w * 64) * 8]);
    };

    // Prologue: A(0), B(0), A(1)   (issue order matters for the vmcnt ledger)
    STAGE_A(0, 0);
    STAGE_B(0, 0);
    STAGE_A(1, 1);

    const int NT = DM / 32;  // 32
    for (int kt = 0; kt < NT; ++kt) {
        if (kt + 1 < NT) asm volatile("s_waitcnt vmcnt(2)" ::: "memory");
        else             asm volatile("s_waitcnt vmcnt(0)" ::: "memory");
        __builtin_amdgcn_sched_barrier(0);
        __builtin_amdgcn_s_barrier();
        __builtin_amdgcn_sched_barrier(0);

        const int ba = kt % 3, bb = kt & 1;
        if (kt + 1 < NT) STAGE_B(kt + 1, bb ^ 1);
        if (kt + 2 < NT) STAGE_A(kt + 2, (ba + 2 >= 3) ? ba - 1 : ba + 2);

        bf16x8 af[4], bf[4];
#pragma unroll
        for (int m = 0; m < 4; ++m)
            af[m] = *(const bf16x8*)&A_lds[ba][(wr * 64 + m * 16 + lc) * 32 + ssw * 8];
#pragma unroll
        for (int n = 0; n < 4; ++n)
            bf[n] = *(const bf16x8*)&B_lds[bb][(wc * 64 + n * 16 + lc) * 32 + ssw * 8];
#pragma unroll
        for (int m = 0; m < 4; ++m)
#pragma unroll
            for (int n = 0; n < 4; ++n)
                acc[m][n] = MFMA16(af[m], bf[n], acc[m][n]);
    }

    float bvv[4];
#pragma unroll
    for (int n = 0; n < 4; ++n) bvv[n] = bias[e * DM + n0 + wc * 64 + n * 16 + lc];

#pragma unroll
    for (int m = 0; m < 4; ++m) {
#pragma unroll
        for (int reg = 0; reg < 4; ++reg) {
            const int rit = wr * 64 + m * 16 + lr * 4 + reg;  // row in tile
            if (rit < valid) {
                const int orow = perm[aRowBase + rit];
                float* op = out + (size_t)orow * DM;
                const unsigned short* xr = Xbf + (size_t)orow * DM;
#pragma unroll
                for (int n = 0; n < 4; ++n) {
                    const int col = n0 + wc * 64 + n * 16 + lc;
                    float v = acc[m][n][reg] + bvv[n];
                    v = v > 0.f ? v : 0.f;
                    op[col] = v + bf2f(xr[col]);
                }
            }
        }
    }
}

// Fallback (small ws): 128x128 2-phase reg-staged f32->bf16.
__global__ __launch_bounds__(256) void k_gemm_small(
        const float* __restrict__ x, const float* __restrict__ W,
        const float* __restrict__ bias, const int* __restrict__ perm,
        const unsigned* __restrict__ ctrl, float* __restrict__ out) {
    __shared__ unsigned short A_lds[128 * 32];
    __shared__ unsigned short B_lds[128 * 32];
    int tb[NE + 1];
    const int total = tile_base(ctrl, tb);
    int bx, ny;
    {
        const int flat = blockIdx.x;
        const int xcd = flat & 7, s2 = flat >> 3;
        bx = xcd * 34 + (s2 >> 3);
        ny = s2 & 7;
    }
    if (bx >= total) return;
    int e = 0;
    while (e < NE - 1 && tb[e + 1] <= bx) ++e;
    const int valid = (int)ctrl[e * 16] - (bx - tb[e]) * 128;
    const int n0 = ny * 128;
    const int t = threadIdx.x, w = t >> 6, l = t & 63;
    const int wr = w >> 1, wc = w & 1;
    const int lc = l & 15, lr = l >> 4;
    const int hsw = ((t & 3) - ((t >> 3) & 3)) & 3;
    const int ssw = (lr + (lc >> 1)) & 3;

    f32x4 acc[4][4];
#pragma unroll
    for (int m = 0; m < 4; ++m)
#pragma unroll
        for (int n = 0; n < 4; ++n) acc[m][n] = (f32x4){0.f, 0.f, 0.f, 0.f};
    const size_t aRowBase = (size_t)bx * 128;

    for (int kt = 0; kt < DM / 32; ++kt) {
        __syncthreads();
#pragma unroll
        for (int rd = 0; rd < 2; ++rd) {
            const int c = rd * 256 + t;
            const int r = c >> 2;
            const float* wp = W + ((size_t)e * DM + n0 + r) * DM + kt * 32 + hsw * 8;
            float4 q0 = *(const float4*)wp;
            float4 q1 = *(const float4*)(wp + 4);
            *(ushort4*)&B_lds[c * 8]     = make_ushort4(f2bf(q0.x), f2bf(q0.y), f2bf(q0.z), f2bf(q0.w));
            *(ushort4*)&B_lds[c * 8 + 4] = make_ushort4(f2bf(q1.x), f2bf(q1.y), f2bf(q1.z), f2bf(q1.w));
            ushort4 p0 = make_ushort4(0, 0, 0, 0), p1 = p0;
            if (r < valid) {
                const int orow = perm[aRowBase + r];
                const float* xp = x + (size_t)orow * DM + kt * 32 + hsw * 8;
                float4 u0 = *(const float4*)xp;
                float4 u1 = *(const float4*)(xp + 4);
                p0 = make_ushort4(f2bf(u0.x), f2bf(u0.y), f2bf(u0.z), f2bf(u0.w));
                p1 = make_ushort4(f2bf(u1.x), f2bf(u1.y), f2bf(u1.z), f2bf(u1.w));
            }
            *(ushort4*)&A_lds[c * 8]     = p0;
            *(ushort4*)&A_lds[c * 8 + 4] = p1;
        }
        __syncthreads();
        bf16x8 af[4], bf[4];
#pragma unroll
        for (int m = 0; m < 4; ++m)
            af[m] = *(const bf16x8*)&A_lds[(wr * 64 + m * 16 + lc) * 32 + ssw * 8];
#pragma unroll
        for (int n = 0; n < 4; ++n)
            bf[n] = *(const bf16x8*)&B_lds[(wc * 64 + n * 16 + lc) * 32 + ssw * 8];
#pragma unroll
        for (int m = 0; m < 4; ++m)
#pragma unroll
            for (int n = 0; n < 4; ++n)
                acc[m][n] = MFMA16(af[m], bf[n], acc[m][n]);
    }

    float bvv[4];
#pragma unroll
    for (int n = 0; n < 4; ++n) bvv[n] = bias[e * DM + n0 + wc * 64 + n * 16 + lc];
#pragma unroll
    for (int m = 0; m < 4; ++m)
#pragma unroll
        for (int reg = 0; reg < 4; ++reg) {
            const int rit = wr * 64 + m * 16 + lr * 4 + reg;
            if (rit < valid) {
                const int orow = perm[aRowBase + rit];
                const float* xr = x + (size_t)orow * DM;
                float* op = out + (size_t)orow * DM;
#pragma unroll
                for (int n = 0; n < 4; ++n) {
                    const int col = n0 + wc * 64 + n * 16 + lc;
                    float v = acc[m][n][reg] + bvv[n];
                    v = v > 0.f ? v : 0.f;
                    op[col] = v + xr[col];
                }
            }
        }
}

extern "C" void kernel_launch(void* const* d_in, const int* in_sizes, int n_in,
                              void* d_out, int out_size, void* d_ws, size_t ws_size,
                              hipStream_t stream) {
    const float* x    = (const float*)d_in[0];
    const float* sig  = (const float*)d_in[1];
    const float* W    = (const float*)d_in[2];
    const float* bias = (const float*)d_in[3];
    float* out = (float*)d_out;
    float* outIdx = out + (size_t)BATCH * DM;

    char* ws = (char*)d_ws;
    int* idx = (int*)ws;
    unsigned* ctrl = (unsigned*)(ws + CTRL_OFF);
    unsigned short* Qbf = (unsigned short*)(ws + QBF_OFF);
    int* perm = (int*)(ws + PERM_OFF);
    unsigned short* Xbf = (unsigned short*)(ws + XBF_OFF);
    unsigned short* Wb = (unsigned short*)(ws + WB_OFF);

    const bool full = ws_size >= WS_NEED;

    k_init<<<64, 256, 0, stream>>>(sig, ctrl, perm, Qbf);
    k_router<<<512, 256, 0, stream>>>(x, Qbf, ctrl, idx, outIdx, Xbf, full ? 1 : 0);
    k_permconv<<<full ? 8320 : 128, 256, 0, stream>>>(idx, ctrl, perm, W, Wb);
    if (full) {
        k_gemm<<<2176, 256, 0, stream>>>(Xbf, Wb, bias, perm, ctrl, out);
    } else {
        k_gemm_small<<<2176, 256, 0, stream>>>(x, W, bias, perm, ctrl, out);
    }
}

// Round 10
// 233.929 us; speedup vs baseline: 1.1975x; 1.0912x over previous
//
#include <hip/hip_runtime.h>
#include <hip/hip_bf16.h>

#define BATCH   32768
#define DM      1024
#define NE      16
#define THRESHF 0.3f
#define MARGIN  0.02f

// ws layout (bytes)
// idx   @ 0          : int32[32768]            = 131072
// ctrl  @ 131072     : u32[2048] (8192 B)
//    [e*16]        counts (one 64B line per expert)
//    [256 + e*16]  cursor (strided)
//    [1024..2047]  packT u32[1024] (pm | mm<<16 per dim)
// Qbf   @ 139264     : bf16[16*1024] ternary   = 32768
// perm  @ 172032     : int32[36864]            = 147456 (prefilled 0)
// Xbf   @ 319488     : bf16[32768*1024]        = 67108864
// Wb    @ 67428352   : bf16[16*1024*1024]      = 33554432  (ends ~96.3 MB)
#define CTRL_OFF 131072
#define QBF_OFF  139264
#define PERM_OFF 172032
#define XBF_OFF  319488
#define WB_OFF   67428352ull
#define WS_NEED  (WB_OFF + (size_t)NE * DM * DM * 2)

typedef __attribute__((ext_vector_type(8))) short bf16x8;
typedef __attribute__((ext_vector_type(4))) float f32x4;

#define MFMA16(a, b, c) __builtin_amdgcn_mfma_f32_16x16x32_bf16(a, b, c, 0, 0, 0)

static __device__ __forceinline__ unsigned short f2bf(float f) {
    union { float f; unsigned u; } v; v.f = f;
    unsigned r = (v.u + 0x7FFFu + ((v.u >> 16) & 1u)) >> 16;  // RNE
    return (unsigned short)r;
}
static __device__ __forceinline__ float bf2f(unsigned short h) {
    union { unsigned u; float f; } v; v.u = ((unsigned)h) << 16;
    return v.f;
}

static __device__ __forceinline__ void gload_lds16(const void* g, void* s) {
    __builtin_amdgcn_global_load_lds(
        (const __attribute__((address_space(1))) void*)g,
        (__attribute__((address_space(3))) void*)s, 16, 0, 0);
}

// Local tile-base from final counts (no k_scan dispatch): 16 adds.
static __device__ __forceinline__ int tile_base(const unsigned* ctrl, int* tb) {
    int acc = 0;
#pragma unroll
    for (int e = 0; e < NE; ++e) {
        tb[e] = acc;
        acc += (int)((ctrl[e * 16] + 127u) >> 7);
    }
    tb[NE] = acc;
    return acc;
}

// Zero ctrl, build ternary pack table + bf16 ternary Q, prefill perm with 0.
__global__ void k_init(const float* __restrict__ sig, unsigned* __restrict__ ctrl,
                       int* __restrict__ perm, unsigned short* __restrict__ Qbf) {
    const int t = blockIdx.x * 256 + threadIdx.x;  // 0..16383
    if (t < 544) ctrl[t] = 0;
    if (t < 1024) {
        unsigned pm = 0, mm = 0;
#pragma unroll
        for (int e = 0; e < NE; ++e) {
            float s = sig[e * DM + t];
            pm |= (s > THRESHF ? 1u : 0u) << e;
            mm |= (s < -THRESHF ? 1u : 0u) << e;
        }
        ctrl[1024 + t] = pm | (mm << 16);
    }
    if (t < 9216) ((int4*)perm)[t] = make_int4(0, 0, 0, 0);
    {   // Qbf[e][d], t = e*1024+d
        float s = sig[t];
        Qbf[t] = s > THRESHF ? (unsigned short)0x3F80u
                             : (s < -THRESHF ? (unsigned short)0xBF80u : (unsigned short)0u);
    }
}

// Fused: blocks 0..511 = MFMA router; blocks 512.. = W f32->bf16 convert.
// The two halves are data-independent, so the conversion's 96 MB of traffic
// overlaps the router's span instead of serializing after it.
// Router: scores = (x_hi @ Q^T) + (x_lo @ Q^T) bf16 MFMA (f32 acc), top-2
// margin; exact f64 fallback for close calls; writes Xbf (= x_hi).
__global__ __launch_bounds__(256) void k_router_conv(
        const float* __restrict__ x,
        const unsigned short* __restrict__ Qbf,
        unsigned* __restrict__ ctrl,
        int* __restrict__ idx,
        float* __restrict__ outIdx,
        unsigned short* __restrict__ Xbf,
        const float* __restrict__ W,
        unsigned short* __restrict__ Wb,
        int writeXbf) {
    if (blockIdx.x >= 512) {   // ---- W conversion part (8192 blocks) ----
        const size_t g = ((size_t)(blockIdx.x - 512) * 256 + threadIdx.x) * 8;
        float4 a = *(const float4*)&W[g];
        float4 b = *(const float4*)&W[g + 4];
        *(ushort4*)&Wb[g]     = make_ushort4(f2bf(a.x), f2bf(a.y), f2bf(a.z), f2bf(a.w));
        *(ushort4*)&Wb[g + 4] = make_ushort4(f2bf(b.x), f2bf(b.y), f2bf(b.z), f2bf(b.w));
        return;
    }

    const int t = threadIdx.x, w = t >> 6, l = t & 63;
    const int lc = l & 15, lr = l >> 4;
    const int wid = blockIdx.x * 4 + w;   // 0..2047
    const int row0 = wid * 16;
    const unsigned* packT = ctrl + 1024;

    const float* ax = x + (size_t)(row0 + lc) * DM + lr * 8;
    const unsigned short* qx = Qbf + (size_t)lc * DM + lr * 8;
    unsigned short* xb = Xbf + (size_t)(row0 + lc) * DM + lr * 8;

    f32x4 acc = (f32x4){0.f, 0.f, 0.f, 0.f};

    for (int kt = 0; kt < 16; ++kt) {
#pragma unroll
        for (int h = 0; h < 2; ++h) {
            const int ko = kt * 64 + h * 32;
            float4 v0 = *(const float4*)(ax + ko);
            float4 v1 = *(const float4*)(ax + ko + 4);
            bf16x8 q = *(const bf16x8*)(qx + ko);

            float f[8] = {v0.x, v0.y, v0.z, v0.w, v1.x, v1.y, v1.z, v1.w};
            bf16x8 ah, al;
#pragma unroll
            for (int j = 0; j < 8; ++j) {
                unsigned short hi = f2bf(f[j]);
                float r = f[j] - bf2f(hi);
                ah[j] = (short)hi;
                al[j] = (short)f2bf(r);
            }
            if (writeXbf) *(bf16x8*)(xb + ko) = ah;
            acc = MFMA16(ah, q, acc);
            acc = MFMA16(al, q, acc);
        }
    }
    // C layout: lane holds scores of expert e=lc for rows lr*4+reg.

    float bv[4]; int bi[4]; float gap[4];
#pragma unroll
    for (int reg = 0; reg < 4; ++reg) {
        float v = acc[reg]; int i = lc; float s = -3.4e38f;
#pragma unroll
        for (int m = 1; m < 16; m <<= 1) {
            float ov = __shfl_xor(v, m, 64);
            int oi = __shfl_xor(i, m, 64);
            float os = __shfl_xor(s, m, 64);
            bool take = (ov > v) || (ov == v && oi < i);
            float loser = take ? v : ov;
            v = take ? ov : v;
            i = take ? oi : i;
            s = fmaxf(fmaxf(s, os), loser);
        }
        bv[reg] = v; bi[reg] = i; gap[reg] = v - s;
    }

    unsigned flagsw = 0;
#pragma unroll
    for (int reg = 0; reg < 4; ++reg)
        flagsw |= (gap[reg] < MARGIN ? 1u : 0u) << reg;

    if (__any(lc == 0 && flagsw != 0)) {   // rare exact path
#pragma unroll
        for (int reg = 0; reg < 4; ++reg) {
            for (int g = 0; g < 4; ++g) {
                const unsigned fw = __shfl(flagsw, g * 16, 64);
                if ((fw >> reg) & 1u) {
                    const int row = row0 + g * 4 + reg;
                    const float* xr = x + (size_t)row * DM;
                    float xv[16]; unsigned mk[16];
#pragma unroll
                    for (int k2 = 0; k2 < 16; ++k2) {
                        xv[k2] = xr[k2 * 64 + l];
                        mk[k2] = packT[k2 * 64 + l];
                    }
                    double best = 0.0; int bbi = 0;
                    for (int e = 0; e < 16; ++e) {
                        double a = 0.0;
#pragma unroll
                        for (int k2 = 0; k2 < 16; ++k2) {
                            const int pb = (int)((mk[k2] >> e) & 1u);
                            const int mb = (int)((mk[k2] >> (16 + e)) & 1u);
                            a += pb ? (double)xv[k2] : (mb ? -(double)xv[k2] : 0.0);
                        }
#pragma unroll
                        for (int m = 1; m < 64; m <<= 1) a += __shfl_xor(a, m, 64);
                        if (e == 0 || a > best) { best = a; bbi = e; }
                    }
                    if (lr == g && lc == 0) bi[reg] = bbi;
                }
            }
        }
    }

    if (lc == 0) {
#pragma unroll
        for (int reg = 0; reg < 4; ++reg) {
            const int row = row0 + lr * 4 + reg;
            idx[row] = bi[reg];
            outIdx[row] = (float)bi[reg];
            atomicAdd(&ctrl[bi[reg] * 16], 1u);
        }
    }
}

// Perm build: block-aggregated ranks (LDS hist -> 16 global atomics/block).
__global__ __launch_bounds__(256) void k_perm(const int* __restrict__ idx,
                                              unsigned* __restrict__ ctrl,
                                              int* __restrict__ perm) {
    __shared__ unsigned hcnt[16];
    __shared__ unsigned hbase[16];
    const int t = threadIdx.x;
    const int row = blockIdx.x * 256 + t;
    int tb[NE + 1];
    tile_base(ctrl, tb);
    if (t < 16) hcnt[t] = 0;
    __syncthreads();
    const int e = idx[row];
    const unsigned lrank = atomicAdd(&hcnt[e], 1u);
    __syncthreads();
    if (t < 16) hbase[t] = atomicAdd(&ctrl[256 + t * 16], hcnt[t]);
    __syncthreads();
    perm[tb[e] * 128 + hbase[e] + lrank] = row;
}

// Grouped bf16 GEMM: 128x128 tile, BK=32, 4 waves (2x2), 16x16x32 MFMA.
// R7 pipeline restored verbatim (proven 142us): A and B BOTH triple-buffered
// (depth-2 slack; R9 proved depth-1 B exposes its L2 latency), vmcnt(4),
// 49KB LDS -> 3 blocks/CU. LDS chunk-swizzle (both-sides) — conflicts 0 (R6).
// Per iter t: wait vmcnt(4) [STAGE(t) landed, STAGE(t+1) 4 ops in flight],
// s_barrier, STAGE(t+2 -> buf (t+2)%3), ds_read buf t%3, 16 MFMA.
__global__ __launch_bounds__(256) void k_gemm(
        const unsigned short* __restrict__ Xbf,
        const unsigned short* __restrict__ Wb,
        const float* __restrict__ bias,
        const int* __restrict__ perm,
        const unsigned* __restrict__ ctrl,
        float* __restrict__ out) {
    __shared__ unsigned short A_lds[3][128 * 32];
    __shared__ unsigned short B_lds[3][128 * 32];

    int tb[NE + 1];
    const int total = tile_base(ctrl, tb);

    // flat = 0..2175: xcd = flat&7; all 8 ny-siblings of one bx share an XCD.
    int bx, ny;
    {
        const int flat = blockIdx.x;
        const int xcd = flat & 7, s2 = flat >> 3;
        bx = xcd * 34 + (s2 >> 3);
        ny = s2 & 7;
    }
    if (bx >= total) return;
    int e = 0;
    while (e < NE - 1 && tb[e + 1] <= bx) ++e;
    const int valid = (int)ctrl[e * 16] - (bx - tb[e]) * 128;  // 1..128
    const int n0 = ny * 128;

    const int t = threadIdx.x, w = t >> 6, l = t & 63;
    const int wr = w >> 1, wc = w & 1;
    const int lc = l & 15, lr = l >> 4;
    const int hsw = ((t & 3) - ((t >> 3) & 3)) & 3;     // staged data-chunk
    const int ssw = (lr + (lc >> 1)) & 3;               // read slot-chunk

    f32x4 acc[4][4];
#pragma unroll
    for (int m = 0; m < 4; ++m)
#pragma unroll
        for (int n = 0; n < 4; ++n) acc[m][n] = (f32x4){0.f, 0.f, 0.f, 0.f};

    const size_t aRowBase = (size_t)bx * 128;
    const unsigned short* Bg = Wb + ((size_t)e * DM + n0) * DM;

    // Per-lane gathered A sources (perm prefilled 0 for pad slots).
    const int r0 = t >> 2;
    const int prow0 = perm[aRowBase + r0];
    const int prow1 = perm[aRowBase + 64 + r0];
    const unsigned short* a0 = Xbf + (size_t)prow0 * DM + hsw * 8;
    const unsigned short* a1 = Xbf + (size_t)prow1 * DM + hsw * 8;
    const unsigned short* b0 = Bg + (size_t)(t >> 2) * DM + hsw * 8;
    const unsigned short* b1 = Bg + (size_t)(64 + (t >> 2)) * DM + hsw * 8;

    auto STAGE = [&](int kt, int buf) {   // 4 VMEM ops/thread
        const int ko = kt * 32;
        gload_lds16(a0 + ko, &A_lds[buf][(size_t)(w * 64) * 8]);
        gload_lds16(a1 + ko, &A_lds[buf][(size_t)(256 + w * 64) * 8]);
        gload_lds16(b0 + ko, &B_lds[buf][(size_t)(w * 64) * 8]);
        gload_lds16(b1 + ko, &B_lds[buf][(size_t)(256 + w * 64) * 8]);
    };

    STAGE(0, 0);
    STAGE(1, 1);

    const int NT = DM / 32;  // 32
    int cur = 0;
    for (int kt = 0; kt < NT; ++kt) {
        if (kt + 1 < NT) asm volatile("s_waitcnt vmcnt(4)" ::: "memory");
        else             asm volatile("s_waitcnt vmcnt(0)" ::: "memory");
        __builtin_amdgcn_sched_barrier(0);
        __builtin_amdgcn_s_barrier();
        __builtin_amdgcn_sched_barrier(0);

        if (kt + 2 < NT) {
            const int nb = (cur + 2 >= 3) ? cur - 1 : cur + 2;
            STAGE(kt + 2, nb);
        }

        bf16x8 af[4], bf[4];
#pragma unroll
        for (int m = 0; m < 4; ++m)
            af[m] = *(const bf16x8*)&A_lds[cur][(wr * 64 + m * 16 + lc) * 32 + ssw * 8];
#pragma unroll
        for (int n = 0; n < 4; ++n)
            bf[n] = *(const bf16x8*)&B_lds[cur][(wc * 64 + n * 16 + lc) * 32 + ssw * 8];
#pragma unroll
        for (int m = 0; m < 4; ++m)
#pragma unroll
            for (int n = 0; n < 4; ++n)
                acc[m][n] = MFMA16(af[m], bf[n], acc[m][n]);

        cur = (cur + 1 >= 3) ? 0 : cur + 1;
    }

    float bvv[4];
#pragma unroll
    for (int n = 0; n < 4; ++n) bvv[n] = bias[e * DM + n0 + wc * 64 + n * 16 + lc];

#pragma unroll
    for (int m = 0; m < 4; ++m) {
#pragma unroll
        for (int reg = 0; reg < 4; ++reg) {
            const int rit = wr * 64 + m * 16 + lr * 4 + reg;  // row in tile
            if (rit < valid) {
                const int orow = perm[aRowBase + rit];
                float* op = out + (size_t)orow * DM;
                const unsigned short* xr = Xbf + (size_t)orow * DM;
#pragma unroll
                for (int n = 0; n < 4; ++n) {
                    const int col = n0 + wc * 64 + n * 16 + lc;
                    float v = acc[m][n][reg] + bvv[n];
                    v = v > 0.f ? v : 0.f;
                    op[col] = v + bf2f(xr[col]);
                }
            }
        }
    }
}

// Fallback (small ws): 128x128 2-phase reg-staged f32->bf16.
__global__ __launch_bounds__(256) void k_gemm_small(
        const float* __restrict__ x, const float* __restrict__ W,
        const float* __restrict__ bias, const int* __restrict__ perm,
        const unsigned* __restrict__ ctrl, float* __restrict__ out) {
    __shared__ unsigned short A_lds[128 * 32];
    __shared__ unsigned short B_lds[128 * 32];
    int tb[NE + 1];
    const int total = tile_base(ctrl, tb);
    int bx, ny;
    {
        const int flat = blockIdx.x;
        const int xcd = flat & 7, s2 = flat >> 3;
        bx = xcd * 34 + (s2 >> 3);
        ny = s2 & 7;
    }
    if (bx >= total) return;
    int e = 0;
    while (e < NE - 1 && tb[e + 1] <= bx) ++e;
    const int valid = (int)ctrl[e * 16] - (bx - tb[e]) * 128;
    const int n0 = ny * 128;
    const int t = threadIdx.x, w = t >> 6, l = t & 63;
    const int wr = w >> 1, wc = w & 1;
    const int lc = l & 15, lr = l >> 4;
    const int hsw = ((t & 3) - ((t >> 3) & 3)) & 3;
    const int ssw = (lr + (lc >> 1)) & 3;

    f32x4 acc[4][4];
#pragma unroll
    for (int m = 0; m < 4; ++m)
#pragma unroll
        for (int n = 0; n < 4; ++n) acc[m][n] = (f32x4){0.f, 0.f, 0.f, 0.f};
    const size_t aRowBase = (size_t)bx * 128;

    for (int kt = 0; kt < DM / 32; ++kt) {
        __syncthreads();
#pragma unroll
        for (int rd = 0; rd < 2; ++rd) {
            const int c = rd * 256 + t;
            const int r = c >> 2;
            const float* wp = W + ((size_t)e * DM + n0 + r) * DM + kt * 32 + hsw * 8;
            float4 q0 = *(const float4*)wp;
            float4 q1 = *(const float4*)(wp + 4);
            *(ushort4*)&B_lds[c * 8]     = make_ushort4(f2bf(q0.x), f2bf(q0.y), f2bf(q0.z), f2bf(q0.w));
            *(ushort4*)&B_lds[c * 8 + 4] = make_ushort4(f2bf(q1.x), f2bf(q1.y), f2bf(q1.z), f2bf(q1.w));
            ushort4 p0 = make_ushort4(0, 0, 0, 0), p1 = p0;
            if (r < valid) {
                const int orow = perm[aRowBase + r];
                const float* xp = x + (size_t)orow * DM + kt * 32 + hsw * 8;
                float4 u0 = *(const float4*)xp;
                float4 u1 = *(const float4*)(xp + 4);
                p0 = make_ushort4(f2bf(u0.x), f2bf(u0.y), f2bf(u0.z), f2bf(u0.w));
                p1 = make_ushort4(f2bf(u1.x), f2bf(u1.y), f2bf(u1.z), f2bf(u1.w));
            }
            *(ushort4*)&A_lds[c * 8]     = p0;
            *(ushort4*)&A_lds[c * 8 + 4] = p1;
        }
        __syncthreads();
        bf16x8 af[4], bf[4];
#pragma unroll
        for (int m = 0; m < 4; ++m)
            af[m] = *(const bf16x8*)&A_lds[(wr * 64 + m * 16 + lc) * 32 + ssw * 8];
#pragma unroll
        for (int n = 0; n < 4; ++n)
            bf[n] = *(const bf16x8*)&B_lds[(wc * 64 + n * 16 + lc) * 32 + ssw * 8];
#pragma unroll
        for (int m = 0; m < 4; ++m)
#pragma unroll
            for (int n = 0; n < 4; ++n)
                acc[m][n] = MFMA16(af[m], bf[n], acc[m][n]);
    }

    float bvv[4];
#pragma unroll
    for (int n = 0; n < 4; ++n) bvv[n] = bias[e * DM + n0 + wc * 64 + n * 16 + lc];
#pragma unroll
    for (int m = 0; m < 4; ++m)
#pragma unroll
        for (int reg = 0; reg < 4; ++reg) {
            const int rit = wr * 64 + m * 16 + lr * 4 + reg;
            if (rit < valid) {
                const int orow = perm[aRowBase + rit];
                const float* xr = x + (size_t)orow * DM;
                float* op = out + (size_t)orow * DM;
#pragma unroll
                for (int n = 0; n < 4; ++n) {
                    const int col = n0 + wc * 64 + n * 16 + lc;
                    float v = acc[m][n][reg] + bvv[n];
                    v = v > 0.f ? v : 0.f;
                    op[col] = v + xr[col];
                }
            }
        }
}

extern "C" void kernel_launch(void* const* d_in, const int* in_sizes, int n_in,
                              void* d_out, int out_size, void* d_ws, size_t ws_size,
                              hipStream_t stream) {
    const float* x    = (const float*)d_in[0];
    const float* sig  = (const float*)d_in[1];
    const float* W    = (const float*)d_in[2];
    const float* bias = (const float*)d_in[3];
    float* out = (float*)d_out;
    float* outIdx = out + (size_t)BATCH * DM;

    char* ws = (char*)d_ws;
    int* idx = (int*)ws;
    unsigned* ctrl = (unsigned*)(ws + CTRL_OFF);
    unsigned short* Qbf = (unsigned short*)(ws + QBF_OFF);
    int* perm = (int*)(ws + PERM_OFF);
    unsigned short* Xbf = (unsigned short*)(ws + XBF_OFF);
    unsigned short* Wb = (unsigned short*)(ws + WB_OFF);

    const bool full = ws_size >= WS_NEED;

    k_init<<<64, 256, 0, stream>>>(sig, ctrl, perm, Qbf);
    k_router_conv<<<full ? 8704 : 512, 256, 0, stream>>>(
        x, Qbf, ctrl, idx, outIdx, Xbf, W, Wb, full ? 1 : 0);
    k_perm<<<128, 256, 0, stream>>>(idx, ctrl, perm);
    if (full) {
        k_gemm<<<2176, 256, 0, stream>>>(Xbf, Wb, bias, perm, ctrl, out);
    } else {
        k_gemm_small<<<2176, 256, 0, stream>>>(x, W, bias, perm, ctrl, out);
    }
}

// Round 11
// 220.937 us; speedup vs baseline: 1.2680x; 1.0588x over previous
//
#include <hip/hip_runtime.h>
#include <hip/hip_bf16.h>

#define BATCH   32768
#define DM      1024
#define NE      16
#define THRESHF 0.3f
#define MARGIN  0.02f

// ws layout (bytes)
// idx   @ 0          : int32[32768]            = 131072
// ctrl  @ 131072     : u32[2048] (8192 B)
//    [e*16]        counts (one 64B line per expert)
//    [256 + e*16]  cursor (strided)
//    [1024..2047]  packT u32[1024] (pm | mm<<16 per dim)
// Qbf   @ 139264     : bf16[16*1024] ternary   = 32768
// perm  @ 172032     : int32[36864]            = 147456 (prefilled 0)
// Xbf   @ 319488     : bf16[32768*1024]        = 67108864
// Wb    @ 67428352   : bf16[16*1024*1024]      = 33554432  (ends ~96.3 MB)
#define CTRL_OFF 131072
#define QBF_OFF  139264
#define PERM_OFF 172032
#define XBF_OFF  319488
#define WB_OFF   67428352ull
#define WS_NEED  (WB_OFF + (size_t)NE * DM * DM * 2)

typedef __attribute__((ext_vector_type(8))) short bf16x8;
typedef __attribute__((ext_vector_type(4))) float f32x4;

#define MFMA16(a, b, c) __builtin_amdgcn_mfma_f32_16x16x32_bf16(a, b, c, 0, 0, 0)

static __device__ __forceinline__ unsigned short f2bf(float f) {
    union { float f; unsigned u; } v; v.f = f;
    unsigned r = (v.u + 0x7FFFu + ((v.u >> 16) & 1u)) >> 16;  // RNE
    return (unsigned short)r;
}
static __device__ __forceinline__ float bf2f(unsigned short h) {
    union { unsigned u; float f; } v; v.u = ((unsigned)h) << 16;
    return v.f;
}

static __device__ __forceinline__ void gload_lds16(const void* g, void* s) {
    __builtin_amdgcn_global_load_lds(
        (const __attribute__((address_space(1))) void*)g,
        (__attribute__((address_space(3))) void*)s, 16, 0, 0);
}

// Local tile-base from final counts (no k_scan dispatch): 16 adds.
static __device__ __forceinline__ int tile_base(const unsigned* ctrl, int* tb) {
    int acc = 0;
#pragma unroll
    for (int e = 0; e < NE; ++e) {
        tb[e] = acc;
        acc += (int)((ctrl[e * 16] + 127u) >> 7);
    }
    tb[NE] = acc;
    return acc;
}

// Zero ctrl, build ternary pack table + bf16 ternary Q, prefill perm with 0.
__global__ void k_init(const float* __restrict__ sig, unsigned* __restrict__ ctrl,
                       int* __restrict__ perm, unsigned short* __restrict__ Qbf) {
    const int t = blockIdx.x * 256 + threadIdx.x;  // 0..16383
    if (t < 544) ctrl[t] = 0;
    if (t < 1024) {
        unsigned pm = 0, mm = 0;
#pragma unroll
        for (int e = 0; e < NE; ++e) {
            float s = sig[e * DM + t];
            pm |= (s > THRESHF ? 1u : 0u) << e;
            mm |= (s < -THRESHF ? 1u : 0u) << e;
        }
        ctrl[1024 + t] = pm | (mm << 16);
    }
    if (t < 9216) ((int4*)perm)[t] = make_int4(0, 0, 0, 0);
    {   // Qbf[e][d], t = e*1024+d
        float s = sig[t];
        Qbf[t] = s > THRESHF ? (unsigned short)0x3F80u
                             : (s < -THRESHF ? (unsigned short)0xBF80u : (unsigned short)0u);
    }
}

// Split-K MFMA router (R11): one block per 16-row group (2048 blocks);
// each of the 4 waves owns a 256-dim K-slice (8 serial iterations vs 32 —
// 4x shorter dependent-load chain, 3x more blocks/CU). Partials combined in
// LDS; wave 0 does argmax + the exact f64 fallback. Xbf written per-slice.
__global__ __launch_bounds__(256) void k_router(const float* __restrict__ x,
                                                const unsigned short* __restrict__ Qbf,
                                                unsigned* __restrict__ ctrl,
                                                int* __restrict__ idx,
                                                float* __restrict__ outIdx,
                                                unsigned short* __restrict__ Xbf,
                                                int writeXbf) {
    __shared__ float S[4][64][4];
    const int t = threadIdx.x, w = t >> 6, l = t & 63;
    const int lc = l & 15, lr = l >> 4;
    const int row0 = blockIdx.x * 16;
    const unsigned* packT = ctrl + 1024;

    const float* ax = x + (size_t)(row0 + lc) * DM + lr * 8;
    const unsigned short* qx = Qbf + (size_t)lc * DM + lr * 8;
    unsigned short* xb = Xbf + (size_t)(row0 + lc) * DM + lr * 8;

    f32x4 acc = (f32x4){0.f, 0.f, 0.f, 0.f};

    for (int kt = w * 4; kt < w * 4 + 4; ++kt) {
#pragma unroll
        for (int h = 0; h < 2; ++h) {
            const int ko = kt * 64 + h * 32;
            float4 v0 = *(const float4*)(ax + ko);
            float4 v1 = *(const float4*)(ax + ko + 4);
            bf16x8 q = *(const bf16x8*)(qx + ko);

            float f[8] = {v0.x, v0.y, v0.z, v0.w, v1.x, v1.y, v1.z, v1.w};
            bf16x8 ah, al;
#pragma unroll
            for (int j = 0; j < 8; ++j) {
                unsigned short hi = f2bf(f[j]);
                float r = f[j] - bf2f(hi);
                ah[j] = (short)hi;
                al[j] = (short)f2bf(r);
            }
            if (writeXbf) *(bf16x8*)(xb + ko) = ah;
            acc = MFMA16(ah, q, acc);
            acc = MFMA16(al, q, acc);
        }
    }
    // C layout: lane holds scores of expert e=lc for rows lr*4+reg (partial).

    *(f32x4*)&S[w][l][0] = acc;
    __syncthreads();
    if (w != 0) return;

#pragma unroll
    for (int s = 1; s < 4; ++s) acc += *(const f32x4*)&S[s][l][0];

    float bv[4]; int bi[4]; float gap[4];
#pragma unroll
    for (int reg = 0; reg < 4; ++reg) {
        float v = acc[reg]; int i = lc; float s = -3.4e38f;
#pragma unroll
        for (int m = 1; m < 16; m <<= 1) {
            float ov = __shfl_xor(v, m, 64);
            int oi = __shfl_xor(i, m, 64);
            float os = __shfl_xor(s, m, 64);
            bool take = (ov > v) || (ov == v && oi < i);
            float loser = take ? v : ov;
            v = take ? ov : v;
            i = take ? oi : i;
            s = fmaxf(fmaxf(s, os), loser);
        }
        bv[reg] = v; bi[reg] = i; gap[reg] = v - s;
    }

    unsigned flagsw = 0;
#pragma unroll
    for (int reg = 0; reg < 4; ++reg)
        flagsw |= (gap[reg] < MARGIN ? 1u : 0u) << reg;

    if (__any(lc == 0 && flagsw != 0)) {   // rare exact path
#pragma unroll
        for (int reg = 0; reg < 4; ++reg) {
            for (int g = 0; g < 4; ++g) {
                const unsigned fw = __shfl(flagsw, g * 16, 64);
                if ((fw >> reg) & 1u) {
                    const int row = row0 + g * 4 + reg;
                    const float* xr = x + (size_t)row * DM;
                    float xv[16]; unsigned mk[16];
#pragma unroll
                    for (int k2 = 0; k2 < 16; ++k2) {
                        xv[k2] = xr[k2 * 64 + l];
                        mk[k2] = packT[k2 * 64 + l];
                    }
                    double best = 0.0; int bbi = 0;
                    for (int e = 0; e < 16; ++e) {
                        double a = 0.0;
#pragma unroll
                        for (int k2 = 0; k2 < 16; ++k2) {
                            const int pb = (int)((mk[k2] >> e) & 1u);
                            const int mb = (int)((mk[k2] >> (16 + e)) & 1u);
                            a += pb ? (double)xv[k2] : (mb ? -(double)xv[k2] : 0.0);
                        }
#pragma unroll
                        for (int m = 1; m < 64; m <<= 1) a += __shfl_xor(a, m, 64);
                        if (e == 0 || a > best) { best = a; bbi = e; }
                    }
                    if (lr == g && lc == 0) bi[reg] = bbi;
                }
            }
        }
    }

    if (lc == 0) {
#pragma unroll
        for (int reg = 0; reg < 4; ++reg) {
            const int row = row0 + lr * 4 + reg;
            idx[row] = bi[reg];
            outIdx[row] = (float)bi[reg];
            atomicAdd(&ctrl[bi[reg] * 16], 1u);
        }
    }
}

// Fused: blocks 0..127 build perm (block-aggregated ranks, local tileBase);
// blocks 128.. convert W f32->bf16 (8 elems/thread). Runs AFTER the router
// (R10 lesson: co-scheduling conv WITH the latency-bound router churns L3
// and starves it; after-router cohabitation with perm measured fine in R9).
__global__ __launch_bounds__(256) void k_permconv(const int* __restrict__ idx,
                                                  unsigned* __restrict__ ctrl,
                                                  int* __restrict__ perm,
                                                  const float* __restrict__ W,
                                                  unsigned short* __restrict__ Wb) {
    if (blockIdx.x >= 128) {
        const size_t g = ((size_t)(blockIdx.x - 128) * 256 + threadIdx.x) * 8;
        float4 a = *(const float4*)&W[g];
        float4 b = *(const float4*)&W[g + 4];
        *(ushort4*)&Wb[g]     = make_ushort4(f2bf(a.x), f2bf(a.y), f2bf(a.z), f2bf(a.w));
        *(ushort4*)&Wb[g + 4] = make_ushort4(f2bf(b.x), f2bf(b.y), f2bf(b.z), f2bf(b.w));
        return;
    }
    __shared__ unsigned hcnt[16];
    __shared__ unsigned hbase[16];
    const int t = threadIdx.x;
    const int row = blockIdx.x * 256 + t;
    int tb[NE + 1];
    tile_base(ctrl, tb);
    if (t < 16) hcnt[t] = 0;
    __syncthreads();
    const int e = idx[row];
    const unsigned lrank = atomicAdd(&hcnt[e], 1u);
    __syncthreads();
    if (t < 16) hbase[t] = atomicAdd(&ctrl[256 + t * 16], hcnt[t]);
    __syncthreads();
    perm[tb[e] * 128 + hbase[e] + lrank] = row;
}

// Grouped bf16 GEMM: 128x128 tile, BK=32, 4 waves (2x2), 16x16x32 MFMA.
// R7 pipeline (proven 142us): A and B triple-buffered (depth-2), vmcnt(4),
// 49KB LDS -> 3 blocks/CU. LDS chunk-swizzle (both-sides) — conflicts 0.
__global__ __launch_bounds__(256) void k_gemm(
        const unsigned short* __restrict__ Xbf,
        const unsigned short* __restrict__ Wb,
        const float* __restrict__ bias,
        const int* __restrict__ perm,
        const unsigned* __restrict__ ctrl,
        float* __restrict__ out) {
    __shared__ unsigned short A_lds[3][128 * 32];
    __shared__ unsigned short B_lds[3][128 * 32];

    int tb[NE + 1];
    const int total = tile_base(ctrl, tb);

    // flat = 0..2175: xcd = flat&7; all 8 ny-siblings of one bx share an XCD.
    int bx, ny;
    {
        const int flat = blockIdx.x;
        const int xcd = flat & 7, s2 = flat >> 3;
        bx = xcd * 34 + (s2 >> 3);
        ny = s2 & 7;
    }
    if (bx >= total) return;
    int e = 0;
    while (e < NE - 1 && tb[e + 1] <= bx) ++e;
    const int valid = (int)ctrl[e * 16] - (bx - tb[e]) * 128;  // 1..128
    const int n0 = ny * 128;

    const int t = threadIdx.x, w = t >> 6, l = t & 63;
    const int wr = w >> 1, wc = w & 1;
    const int lc = l & 15, lr = l >> 4;
    const int hsw = ((t & 3) - ((t >> 3) & 3)) & 3;     // staged data-chunk
    const int ssw = (lr + (lc >> 1)) & 3;               // read slot-chunk

    f32x4 acc[4][4];
#pragma unroll
    for (int m = 0; m < 4; ++m)
#pragma unroll
        for (int n = 0; n < 4; ++n) acc[m][n] = (f32x4){0.f, 0.f, 0.f, 0.f};

    const size_t aRowBase = (size_t)bx * 128;
    const unsigned short* Bg = Wb + ((size_t)e * DM + n0) * DM;

    // Per-lane gathered A sources (perm prefilled 0 for pad slots).
    const int r0 = t >> 2;
    const int prow0 = perm[aRowBase + r0];
    const int prow1 = perm[aRowBase + 64 + r0];
    const unsigned short* a0 = Xbf + (size_t)prow0 * DM + hsw * 8;
    const unsigned short* a1 = Xbf + (size_t)prow1 * DM + hsw * 8;
    const unsigned short* b0 = Bg + (size_t)(t >> 2) * DM + hsw * 8;
    const unsigned short* b1 = Bg + (size_t)(64 + (t >> 2)) * DM + hsw * 8;

    auto STAGE = [&](int kt, int buf) {   // 4 VMEM ops/thread
        const int ko = kt * 32;
        gload_lds16(a0 + ko, &A_lds[buf][(size_t)(w * 64) * 8]);
        gload_lds16(a1 + ko, &A_lds[buf][(size_t)(256 + w * 64) * 8]);
        gload_lds16(b0 + ko, &B_lds[buf][(size_t)(w * 64) * 8]);
        gload_lds16(b1 + ko, &B_lds[buf][(size_t)(256 + w * 64) * 8]);
    };

    STAGE(0, 0);
    STAGE(1, 1);

    const int NT = DM / 32;  // 32
    int cur = 0;
    for (int kt = 0; kt < NT; ++kt) {
        if (kt + 1 < NT) asm volatile("s_waitcnt vmcnt(4)" ::: "memory");
        else             asm volatile("s_waitcnt vmcnt(0)" ::: "memory");
        __builtin_amdgcn_sched_barrier(0);
        __builtin_amdgcn_s_barrier();
        __builtin_amdgcn_sched_barrier(0);

        if (kt + 2 < NT) {
            const int nb = (cur + 2 >= 3) ? cur - 1 : cur + 2;
            STAGE(kt + 2, nb);
        }

        bf16x8 af[4], bf[4];
#pragma unroll
        for (int m = 0; m < 4; ++m)
            af[m] = *(const bf16x8*)&A_lds[cur][(wr * 64 + m * 16 + lc) * 32 + ssw * 8];
#pragma unroll
        for (int n = 0; n < 4; ++n)
            bf[n] = *(const bf16x8*)&B_lds[cur][(wc * 64 + n * 16 + lc) * 32 + ssw * 8];
#pragma unroll
        for (int m = 0; m < 4; ++m)
#pragma unroll
            for (int n = 0; n < 4; ++n)
                acc[m][n] = MFMA16(af[m], bf[n], acc[m][n]);

        cur = (cur + 1 >= 3) ? 0 : cur + 1;
    }

    float bvv[4];
#pragma unroll
    for (int n = 0; n < 4; ++n) bvv[n] = bias[e * DM + n0 + wc * 64 + n * 16 + lc];

#pragma unroll
    for (int m = 0; m < 4; ++m) {
#pragma unroll
        for (int reg = 0; reg < 4; ++reg) {
            const int rit = wr * 64 + m * 16 + lr * 4 + reg;  // row in tile
            if (rit < valid) {
                const int orow = perm[aRowBase + rit];
                float* op = out + (size_t)orow * DM;
                const unsigned short* xr = Xbf + (size_t)orow * DM;
#pragma unroll
                for (int n = 0; n < 4; ++n) {
                    const int col = n0 + wc * 64 + n * 16 + lc;
                    float v = acc[m][n][reg] + bvv[n];
                    v = v > 0.f ? v : 0.f;
                    op[col] = v + bf2f(xr[col]);
                }
            }
        }
    }
}

// Fallback (small ws): 128x128 2-phase reg-staged f32->bf16.
__global__ __launch_bounds__(256) void k_gemm_small(
        const float* __restrict__ x, const float* __restrict__ W,
        const float* __restrict__ bias, const int* __restrict__ perm,
        const unsigned* __restrict__ ctrl, float* __restrict__ out) {
    __shared__ unsigned short A_lds[128 * 32];
    __shared__ unsigned short B_lds[128 * 32];
    int tb[NE + 1];
    const int total = tile_base(ctrl, tb);
    int bx, ny;
    {
        const int flat = blockIdx.x;
        const int xcd = flat & 7, s2 = flat >> 3;
        bx = xcd * 34 + (s2 >> 3);
        ny = s2 & 7;
    }
    if (bx >= total) return;
    int e = 0;
    while (e < NE - 1 && tb[e + 1] <= bx) ++e;
    const int valid = (int)ctrl[e * 16] - (bx - tb[e]) * 128;
    const int n0 = ny * 128;
    const int t = threadIdx.x, w = t >> 6, l = t & 63;
    const int wr = w >> 1, wc = w & 1;
    const int lc = l & 15, lr = l >> 4;
    const int hsw = ((t & 3) - ((t >> 3) & 3)) & 3;
    const int ssw = (lr + (lc >> 1)) & 3;

    f32x4 acc[4][4];
#pragma unroll
    for (int m = 0; m < 4; ++m)
#pragma unroll
        for (int n = 0; n < 4; ++n) acc[m][n] = (f32x4){0.f, 0.f, 0.f, 0.f};
    const size_t aRowBase = (size_t)bx * 128;

    for (int kt = 0; kt < DM / 32; ++kt) {
        __syncthreads();
#pragma unroll
        for (int rd = 0; rd < 2; ++rd) {
            const int c = rd * 256 + t;
            const int r = c >> 2;
            const float* wp = W + ((size_t)e * DM + n0 + r) * DM + kt * 32 + hsw * 8;
            float4 q0 = *(const float4*)wp;
            float4 q1 = *(const float4*)(wp + 4);
            *(ushort4*)&B_lds[c * 8]     = make_ushort4(f2bf(q0.x), f2bf(q0.y), f2bf(q0.z), f2bf(q0.w));
            *(ushort4*)&B_lds[c * 8 + 4] = make_ushort4(f2bf(q1.x), f2bf(q1.y), f2bf(q1.z), f2bf(q1.w));
            ushort4 p0 = make_ushort4(0, 0, 0, 0), p1 = p0;
            if (r < valid) {
                const int orow = perm[aRowBase + r];
                const float* xp = x + (size_t)orow * DM + kt * 32 + hsw * 8;
                float4 u0 = *(const float4*)xp;
                float4 u1 = *(const float4*)(xp + 4);
                p0 = make_ushort4(f2bf(u0.x), f2bf(u0.y), f2bf(u0.z), f2bf(u0.w));
                p1 = make_ushort4(f2bf(u1.x), f2bf(u1.y), f2bf(u1.z), f2bf(u1.w));
            }
            *(ushort4*)&A_lds[c * 8]     = p0;
            *(ushort4*)&A_lds[c * 8 + 4] = p1;
        }
        __syncthreads();
        bf16x8 af[4], bf[4];
#pragma unroll
        for (int m = 0; m < 4; ++m)
            af[m] = *(const bf16x8*)&A_lds[(wr * 64 + m * 16 + lc) * 32 + ssw * 8];
#pragma unroll
        for (int n = 0; n < 4; ++n)
            bf[n] = *(const bf16x8*)&B_lds[(wc * 64 + n * 16 + lc) * 32 + ssw * 8];
#pragma unroll
        for (int m = 0; m < 4; ++m)
#pragma unroll
            for (int n = 0; n < 4; ++n)
                acc[m][n] = MFMA16(af[m], bf[n], acc[m][n]);
    }

    float bvv[4];
#pragma unroll
    for (int n = 0; n < 4; ++n) bvv[n] = bias[e * DM + n0 + wc * 64 + n * 16 + lc];
#pragma unroll
    for (int m = 0; m < 4; ++m)
#pragma unroll
        for (int reg = 0; reg < 4; ++reg) {
            const int rit = wr * 64 + m * 16 + lr * 4 + reg;
            if (rit < valid) {
                const int orow = perm[aRowBase + rit];
                const float* xr = x + (size_t)orow * DM;
                float* op = out + (size_t)orow * DM;
#pragma unroll
                for (int n = 0; n < 4; ++n) {
                    const int col = n0 + wc * 64 + n * 16 + lc;
                    float v = acc[m][n][reg] + bvv[n];
                    v = v > 0.f ? v : 0.f;
                    op[col] = v + xr[col];
                }
            }
        }
}

extern "C" void kernel_launch(void* const* d_in, const int* in_sizes, int n_in,
                              void* d_out, int out_size, void* d_ws, size_t ws_size,
                              hipStream_t stream) {
    const float* x    = (const float*)d_in[0];
    const float* sig  = (const float*)d_in[1];
    const float* W    = (const float*)d_in[2];
    const float* bias = (const float*)d_in[3];
    float* out = (float*)d_out;
    float* outIdx = out + (size_t)BATCH * DM;

    char* ws = (char*)d_ws;
    int* idx = (int*)ws;
    unsigned* ctrl = (unsigned*)(ws + CTRL_OFF);
    unsigned short* Qbf = (unsigned short*)(ws + QBF_OFF);
    int* perm = (int*)(ws + PERM_OFF);
    unsigned short* Xbf = (unsigned short*)(ws + XBF_OFF);
    unsigned short* Wb = (unsigned short*)(ws + WB_OFF);

    const bool full = ws_size >= WS_NEED;

    k_init<<<64, 256, 0, stream>>>(sig, ctrl, perm, Qbf);
    k_router<<<2048, 256, 0, stream>>>(x, Qbf, ctrl, idx, outIdx, Xbf, full ? 1 : 0);
    k_permconv<<<full ? 8320 : 128, 256, 0, stream>>>(idx, ctrl, perm, W, Wb);
    if (full) {
        k_gemm<<<2176, 256, 0, stream>>>(Xbf, Wb, bias, perm, ctrl, out);
    } else {
        k_gemm_small<<<2176, 256, 0, stream>>>(x, W, bias, perm, ctrl, out);
    }
}